// Round 1
// baseline (2795.783 us; speedup 1.0000x reference)
//
#include <hip/hip_runtime.h>
#include <hip/hip_bf16.h>
#include <stdint.h>

#define EE 400000
#define NP 100000
#define NL 80000
#define NG 50000
#define SMAX 100000  // per-relation score/denom stride

typedef __attribute__((ext_vector_type(4))) float f32x4;
typedef __attribute__((ext_vector_type(8))) short bf16x8;

__device__ __forceinline__ short f2bf(float f) {
  union { float f; uint32_t u; } v; v.f = f;
  uint32_t r = v.u + 0x7fffu + ((v.u >> 16) & 1u);
  return (short)(r >> 16);
}

// ---------------- Wt: W[r][k][n] fp32 -> Wt[r][n][k] bf16 ----------------
__global__ void wt_kernel(const float* __restrict__ W, short* __restrict__ Wt) {
  int idx = blockIdx.x * 256 + threadIdx.x;  // over 9*512*128
  if (idx >= 9 * 512 * 128) return;
  int n = idx & 127;
  int k = (idx >> 7) & 511;
  int r = idx >> 16;
  Wt[((size_t)r * 128 + n) * 512 + k] = f2bf(W[idx]);
}

// ---------------- v[r][which][k] = sum_n W[r][k][n] * att[r][n] ----------------
__global__ void v_kernel(const float* __restrict__ W, const float* __restrict__ att_src,
                         const float* __restrict__ att_dst, float* __restrict__ v) {
  int r = blockIdx.x >> 1, which = blockIdx.x & 1;
  const float* att = (which ? att_dst : att_src) + (size_t)r * 128;
  int k = threadIdx.x;  // 0..511
  const float* Wrow = W + ((size_t)r * 512 + k) * 128;
  float s = 0.0f;
  for (int n = 0; n < 128; n++) s += Wrow[n] * att[n];
  v[((size_t)r * 2 + which) * 512 + k] = s;
}

// ---------------- scores: per row of x, 6 dots with v-vectors (fp32 exact) ----------------
__global__ void scores_kernel(const float* __restrict__ x, int N, int srcBase,
                              int dr0, int dr1, int dr2,
                              const float* __restrict__ v,
                              float* __restrict__ Ssrc, float* __restrict__ Sdst) {
  int tid = threadIdx.x;
  int lane = tid & 63, wave = tid >> 6;
  int rels[6] = {srcBase, srcBase + 1, srcBase + 2, dr0, dr1, dr2};
  float vr[6][8];
#pragma unroll
  for (int j = 0; j < 6; j++) {
    int which = (j < 3) ? 0 : 1;
    const float* vp = v + ((size_t)rels[j] * 2 + which) * 512 + lane * 8;
#pragma unroll
    for (int m = 0; m < 8; m++) vr[j][m] = vp[m];
  }
  int stride = (blockDim.x >> 6) * gridDim.x;
  for (int row = blockIdx.x * (blockDim.x >> 6) + wave; row < N; row += stride) {
    const f32x4* xr = (const f32x4*)(x + (size_t)row * 512);
    f32x4 a = xr[lane * 2], b = xr[lane * 2 + 1];
    float p[6];
#pragma unroll
    for (int j = 0; j < 6; j++) {
      p[j] = a.x * vr[j][0] + a.y * vr[j][1] + a.z * vr[j][2] + a.w * vr[j][3] +
             b.x * vr[j][4] + b.y * vr[j][5] + b.z * vr[j][6] + b.w * vr[j][7];
    }
#pragma unroll
    for (int off = 32; off >= 1; off >>= 1) {
#pragma unroll
      for (int j = 0; j < 6; j++) p[j] += __shfl_xor(p[j], off);
    }
    if (lane == 0) {
      Ssrc[(size_t)rels[0] * SMAX + row] = p[0];
      Ssrc[(size_t)rels[1] * SMAX + row] = p[1];
      Ssrc[(size_t)rels[2] * SMAX + row] = p[2];
      Sdst[(size_t)rels[3] * SMAX + row] = p[3];
      Sdst[(size_t)rels[4] * SMAX + row] = p[4];
      Sdst[(size_t)rels[5] * SMAX + row] = p[5];
    }
  }
}

// ---------------- GEMM: H[N x 128] = x[N x 512] @ W_r  (bf16 MFMA, fp32 out) ----------------
__global__ __launch_bounds__(256, 2)
void gemm_kernel(const float* __restrict__ x, const short* __restrict__ Wt,
                 float* __restrict__ H, int N) {
  __shared__ short As[2][128][40];  // 128 rows x 32 k, pad to 40 (80B rows -> 2-way banks)
  __shared__ short Bs[2][128][40];  // 128 cols x 32 k (W transposed), same pad

  int tid = threadIdx.x;
  int wave = tid >> 6, lane = tid & 63;
  int row0 = blockIdx.x * 128;

  // A staging: thread -> (row = tid>>1, k-half = (tid&1)*16), 16 fp32 -> 16 bf16
  int arow = tid >> 1;
  int akh = (tid & 1) * 16;
  bool avalid = (row0 + arow) < N;
  const float* aptr = x + (size_t)(row0 + arow) * 512 + akh;

  // B staging: thread -> (col n = tid&127, k-half = (tid>>7)*16), 16 bf16 direct
  int bn = tid & 127;
  int bkh = (tid >> 7) * 16;
  const short* bptr = Wt + (size_t)bn * 512 + bkh;

  int frow = lane & 15;
  int fko = (lane >> 4) * 8;

  f32x4 acc[2][8];
#pragma unroll
  for (int i = 0; i < 2; i++)
#pragma unroll
    for (int j = 0; j < 8; j++) acc[i][j] = (f32x4)0.0f;

  f32x4 a0, a1, a2, a3;
  bf16x8 b0, b1;

#define STAGE_LOAD(T)                                              \
  {                                                                \
    if (avalid) {                                                  \
      const f32x4* ap = (const f32x4*)(aptr + (T) * 32);           \
      a0 = ap[0]; a1 = ap[1]; a2 = ap[2]; a3 = ap[3];              \
    } else {                                                       \
      a0 = (f32x4)0.0f; a1 = (f32x4)0.0f;                          \
      a2 = (f32x4)0.0f; a3 = (f32x4)0.0f;                          \
    }                                                              \
    const short* bp = bptr + (T) * 32;                             \
    b0 = *(const bf16x8*)bp;                                       \
    b1 = *(const bf16x8*)(bp + 8);                                 \
  }

#define STAGE_WRITE(BUF)                                           \
  {                                                                \
    bf16x8 t0, t1;                                                 \
    t0[0] = f2bf(a0.x); t0[1] = f2bf(a0.y); t0[2] = f2bf(a0.z);    \
    t0[3] = f2bf(a0.w); t0[4] = f2bf(a1.x); t0[5] = f2bf(a1.y);    \
    t0[6] = f2bf(a1.z); t0[7] = f2bf(a1.w);                        \
    t1[0] = f2bf(a2.x); t1[1] = f2bf(a2.y); t1[2] = f2bf(a2.z);    \
    t1[3] = f2bf(a2.w); t1[4] = f2bf(a3.x); t1[5] = f2bf(a3.y);    \
    t1[6] = f2bf(a3.z); t1[7] = f2bf(a3.w);                        \
    *(bf16x8*)&As[BUF][arow][akh] = t0;                            \
    *(bf16x8*)&As[BUF][arow][akh + 8] = t1;                        \
    *(bf16x8*)&Bs[BUF][bn][bkh] = b0;                              \
    *(bf16x8*)&Bs[BUF][bn][bkh + 8] = b1;                          \
  }

  STAGE_LOAD(0)
  STAGE_WRITE(0)
  __syncthreads();

  for (int t = 0; t < 16; t++) {
    if (t < 15) STAGE_LOAD(t + 1)
    int cur = t & 1;
    bf16x8 af0 = *(const bf16x8*)&As[cur][wave * 32 + frow][fko];
    bf16x8 af1 = *(const bf16x8*)&As[cur][wave * 32 + 16 + frow][fko];
    bf16x8 bfr[8];
#pragma unroll
    for (int ct = 0; ct < 8; ct++)
      bfr[ct] = *(const bf16x8*)&Bs[cur][ct * 16 + frow][fko];
#pragma unroll
    for (int ct = 0; ct < 8; ct++) {
      acc[0][ct] = __builtin_amdgcn_mfma_f32_16x16x32_bf16(af0, bfr[ct], acc[0][ct], 0, 0, 0);
      acc[1][ct] = __builtin_amdgcn_mfma_f32_16x16x32_bf16(af1, bfr[ct], acc[1][ct], 0, 0, 0);
    }
    if (t < 15) STAGE_WRITE((t + 1) & 1)
    __syncthreads();
  }

  // epilogue: C/D layout col = lane&15, row = (lane>>4)*4 + j  (m89-verified)
  int r4 = (lane >> 4) * 4;
  int cc = lane & 15;
#pragma unroll
  for (int rt = 0; rt < 2; rt++) {
    int rowb = row0 + wave * 32 + rt * 16 + r4;
#pragma unroll
    for (int ct = 0; ct < 8; ct++) {
      int col = ct * 16 + cc;
#pragma unroll
      for (int j = 0; j < 4; j++) {
        if (rowb + j < N) H[(size_t)(rowb + j) * 128 + col] = acc[rt][ct][j];
      }
    }
  }
#undef STAGE_LOAD
#undef STAGE_WRITE
}

// ---------------- per-edge weight + denom (all 9 relations batched) ----------------
struct EdgePtrs { const int* p[9]; };

__global__ void edge_w_kernel(EdgePtrs ep, const float* __restrict__ Ssrc,
                              const float* __restrict__ Sdst,
                              float* __restrict__ w_e, float* __restrict__ denom) {
  int r = blockIdx.y;
  int e = blockIdx.x * 256 + threadIdx.x;
  if (e >= EE) return;
  const int* ei = ep.p[r];
  int s = ei[e], d = ei[EE + e];
  float a = Ssrc[(size_t)r * SMAX + s] + Sdst[(size_t)r * SMAX + d];
  float alpha = a > 0.0f ? a : 0.2f * a;
  float w = expf(alpha);  // no max-subtraction needed: |alpha| <~ 9
  w_e[(size_t)r * EE + e] = w;
  atomicAdd(&denom[(size_t)r * SMAX + d], w);
}

// ---------------- scatter: out[dst] += h_src[src] * w/denom  (128 lanes/edge) ----------------
__global__ void scatter_kernel(const int* __restrict__ ei, const float* __restrict__ w_e,
                               const float* __restrict__ denom, const float* __restrict__ H,
                               float* __restrict__ outp) {
  int t = blockIdx.x * 256 + threadIdx.x;
  int e = t >> 7;
  if (e >= EE) return;
  int c = t & 127;
  int s = ei[e], d = ei[EE + e];
  float scale = w_e[e] / denom[d];
  atomicAdd(&outp[(size_t)d * 128 + c], H[(size_t)s * 128 + c] * scale);
}

// ---------------- finalize: relu((acc + sum bias)/3) in-place ----------------
__global__ void finalize_kernel(float* __restrict__ out, const float* __restrict__ bias) {
  int idx = blockIdx.x * 256 + threadIdx.x;  // float4 index
  if (idx >= 7360000) return;
  size_t f = (size_t)idx * 4;
  int col = (int)(f & 127);
  int r0, r1, r2;
  if (f < (size_t)NP * 128)            { r0 = 0; r1 = 4; r2 = 7; }
  else if (f < (size_t)(NP + NL) * 128){ r0 = 1; r1 = 3; r2 = 8; }
  else                                 { r0 = 2; r1 = 5; r2 = 6; }
  f32x4 vv = *(f32x4*)(out + f);
#pragma unroll
  for (int j = 0; j < 4; j++) {
    float b = bias[r0 * 128 + col + j] + bias[r1 * 128 + col + j] + bias[r2 * 128 + col + j];
    float val = (vv[j] + b) * (1.0f / 3.0f);
    vv[j] = val > 0.0f ? val : 0.0f;
  }
  *(f32x4*)(out + f) = vv;
}

// ---------------- orchestration ----------------
extern "C" void kernel_launch(void* const* d_in, const int* in_sizes, int n_in,
                              void* d_out, int out_size, void* d_ws, size_t ws_size,
                              hipStream_t stream) {
  const float* x[3] = {(const float*)d_in[0], (const float*)d_in[1], (const float*)d_in[2]};
  const int* ei[9];
  for (int i = 0; i < 9; i++) ei[i] = (const int*)d_in[3 + i];
  const float* W = (const float*)d_in[12];
  const float* att_src = (const float*)d_in[13];
  const float* att_dst = (const float*)d_in[14];
  const float* bias = (const float*)d_in[15];

  char* ws = (char*)d_ws;
  short* Wt    = (short*)(ws + 0);          // 1,179,648 B
  float* v     = (float*)(ws + 1179648);    //    36,864 B
  float* Ssrc  = (float*)(ws + 1216512);    // 3,600,128 B
  float* Sdst  = (float*)(ws + 4816640);    // 3,600,128 B
  float* w_e   = (float*)(ws + 8416768);    // 14,400,000 B
  float* denom = (float*)(ws + 22816768);   // 3,600,128 B
  float* H     = (float*)(ws + 26416896);   // 51,200,000 B  (total ~74 MB)

  hipMemsetAsync(d_out, 0, (size_t)out_size * 4, stream);
  hipMemsetAsync(denom, 0, (size_t)9 * SMAX * 4, stream);

  wt_kernel<<<dim3((9 * 512 * 128 + 255) / 256), dim3(256), 0, stream>>>(W, Wt);
  v_kernel<<<dim3(18), dim3(512), 0, stream>>>(W, att_src, att_dst, v);

  // src relations for type T are {3T,3T+1,3T+2}; dst relations per type from RELS table
  scores_kernel<<<dim3(1024), dim3(256), 0, stream>>>(x[0], NP, 0, 0, 4, 7, v, Ssrc, Sdst);
  scores_kernel<<<dim3(1024), dim3(256), 0, stream>>>(x[1], NL, 3, 1, 3, 8, v, Ssrc, Sdst);
  scores_kernel<<<dim3(1024), dim3(256), 0, stream>>>(x[2], NG, 6, 2, 5, 6, v, Ssrc, Sdst);

  EdgePtrs ep;
  for (int i = 0; i < 9; i++) ep.p[i] = ei[i];
  edge_w_kernel<<<dim3((EE + 255) / 256, 9), dim3(256), 0, stream>>>(ep, Ssrc, Sdst, w_e, denom);

  static const int srcT[9] = {0, 0, 0, 1, 1, 1, 2, 2, 2};
  static const int dstT[9] = {0, 1, 2, 1, 0, 2, 2, 0, 1};
  static const int Ns[3] = {NP, NL, NG};
  static const size_t outOff[3] = {0, (size_t)NP * 128, (size_t)(NP + NL) * 128};

  for (int r = 0; r < 9; r++) {
    int s = srcT[r], d = dstT[r];
    gemm_kernel<<<dim3((Ns[s] + 127) / 128), dim3(256), 0, stream>>>(
        x[s], Wt + (size_t)r * 128 * 512, H, Ns[s]);
    scatter_kernel<<<dim3(EE * 128 / 256), dim3(256), 0, stream>>>(
        ei[r], w_e + (size_t)r * EE, denom + (size_t)r * SMAX, H,
        (float*)d_out + outOff[d]);
  }

  finalize_kernel<<<dim3((7360000 + 255) / 256), dim3(256), 0, stream>>>((float*)d_out, bias);
}

// Round 3
// 2000.288 us; speedup vs baseline: 1.3977x; 1.3977x over previous
//
#include <hip/hip_runtime.h>
#include <hip/hip_bf16.h>
#include <stdint.h>

#define EE 400000
#define NP 100000
#define NL 80000
#define NG 50000
#define SMAX 100000   // per-relation score/count stride
#define NCNT 900000   // 9 * SMAX

typedef __attribute__((ext_vector_type(4))) float f32x4;
typedef __attribute__((ext_vector_type(8))) short bf16x8;

__device__ __forceinline__ short f2bf(float f) {
  union { float f; uint32_t u; } v; v.f = f;
  uint32_t r = v.u + 0x7fffu + ((v.u >> 16) & 1u);
  return (short)(r >> 16);
}

__device__ __forceinline__ float bf2f(uint32_t lo16) {
  union { uint32_t u; float f; } v; v.u = lo16 << 16;
  return v.f;
}

struct EdgePtrs { const int* p[9]; };

// ---------------- Wt: W[r][k][n] fp32 -> Wt[r][n][k] bf16 ----------------
__global__ void wt_kernel(const float* __restrict__ W, short* __restrict__ Wt) {
  int idx = blockIdx.x * 256 + threadIdx.x;  // over 9*512*128
  if (idx >= 9 * 512 * 128) return;
  int n = idx & 127;
  int k = (idx >> 7) & 511;
  int r = idx >> 16;
  Wt[((size_t)r * 128 + n) * 512 + k] = f2bf(W[idx]);
}

// ---------------- v[r][which][k] = sum_n W[r][k][n] * att[r][n] ----------------
__global__ void v_kernel(const float* __restrict__ W, const float* __restrict__ att_src,
                         const float* __restrict__ att_dst, float* __restrict__ v) {
  int r = blockIdx.x >> 1, which = blockIdx.x & 1;
  const float* att = (which ? att_dst : att_src) + (size_t)r * 128;
  int k = threadIdx.x;  // 0..511
  const float* Wrow = W + ((size_t)r * 512 + k) * 128;
  float s = 0.0f;
  for (int n = 0; n < 128; n++) s += Wrow[n] * att[n];
  v[((size_t)r * 2 + which) * 512 + k] = s;
}

// ---------------- scores: per row of x, 6 dots with v-vectors (fp32 exact) ----------------
__global__ void scores_kernel(const float* __restrict__ x, int N, int srcBase,
                              int dr0, int dr1, int dr2,
                              const float* __restrict__ v,
                              float* __restrict__ Ssrc, float* __restrict__ Sdst) {
  int tid = threadIdx.x;
  int lane = tid & 63, wave = tid >> 6;
  int rels[6] = {srcBase, srcBase + 1, srcBase + 2, dr0, dr1, dr2};
  float vr[6][8];
#pragma unroll
  for (int j = 0; j < 6; j++) {
    int which = (j < 3) ? 0 : 1;
    const float* vp = v + ((size_t)rels[j] * 2 + which) * 512 + lane * 8;
#pragma unroll
    for (int m = 0; m < 8; m++) vr[j][m] = vp[m];
  }
  int stride = (blockDim.x >> 6) * gridDim.x;
  for (int row = blockIdx.x * (blockDim.x >> 6) + wave; row < N; row += stride) {
    const f32x4* xr = (const f32x4*)(x + (size_t)row * 512);
    f32x4 a = xr[lane * 2], b = xr[lane * 2 + 1];
    float p[6];
#pragma unroll
    for (int j = 0; j < 6; j++) {
      p[j] = a.x * vr[j][0] + a.y * vr[j][1] + a.z * vr[j][2] + a.w * vr[j][3] +
             b.x * vr[j][4] + b.y * vr[j][5] + b.z * vr[j][6] + b.w * vr[j][7];
    }
#pragma unroll
    for (int off = 32; off >= 1; off >>= 1) {
#pragma unroll
      for (int j = 0; j < 6; j++) p[j] += __shfl_xor(p[j], off);
    }
    if (lane == 0) {
      Ssrc[(size_t)rels[0] * SMAX + row] = p[0];
      Ssrc[(size_t)rels[1] * SMAX + row] = p[1];
      Ssrc[(size_t)rels[2] * SMAX + row] = p[2];
      Sdst[(size_t)rels[3] * SMAX + row] = p[3];
      Sdst[(size_t)rels[4] * SMAX + row] = p[4];
      Sdst[(size_t)rels[5] * SMAX + row] = p[5];
    }
  }
}

// ---------------- CSR build: histogram -> scan -> reorder ----------------
__global__ void hist_kernel(EdgePtrs ep, int* __restrict__ cnt) {
  int r = blockIdx.y;
  int e = blockIdx.x * 256 + threadIdx.x;
  if (e >= EE) return;
  int d = ep.p[r][EE + e];
  atomicAdd(&cnt[r * SMAX + d], 1);
}

__global__ void scan1_kernel(const int* __restrict__ cnt, int* __restrict__ bsum) {
  __shared__ int sm[256];
  int t = threadIdx.x;
  int base = blockIdx.x * 1024 + t * 4;
  int s = 0;
#pragma unroll
  for (int i = 0; i < 4; i++) { int idx = base + i; if (idx < NCNT) s += cnt[idx]; }
  sm[t] = s; __syncthreads();
  for (int o = 128; o >= 1; o >>= 1) { if (t < o) sm[t] += sm[t + o]; __syncthreads(); }
  if (t == 0) bsum[blockIdx.x] = sm[0];
}

__global__ void scan2_kernel(int* __restrict__ bsum, int nb) {
  __shared__ int sm[1024];
  int t = threadIdx.x;
  int vv = (t < nb) ? bsum[t] : 0;
  sm[t] = vv; __syncthreads();
  for (int o = 1; o < 1024; o <<= 1) {
    int add = (t >= o) ? sm[t - o] : 0;
    __syncthreads();
    sm[t] += add;
    __syncthreads();
  }
  if (t < nb) bsum[t] = sm[t] - vv;  // exclusive
}

__global__ void scan3_kernel(const int* __restrict__ cnt, const int* __restrict__ bsum,
                             int* __restrict__ off, int* __restrict__ cursor) {
  __shared__ int sm[256];
  int t = threadIdx.x;
  int base = blockIdx.x * 1024 + t * 4;
  int e[4]; int s = 0;
#pragma unroll
  for (int i = 0; i < 4; i++) {
    int idx = base + i;
    int c = (idx < NCNT) ? cnt[idx] : 0;
    e[i] = s; s += c;
  }
  int tot = s;
  sm[t] = s; __syncthreads();
  for (int o = 1; o < 256; o <<= 1) {
    int add = (t >= o) ? sm[t - o] : 0;
    __syncthreads();
    sm[t] += add;
    __syncthreads();
  }
  int texcl = sm[t] - tot;
  int b0 = bsum[blockIdx.x];
#pragma unroll
  for (int i = 0; i < 4; i++) {
    int idx = base + i;
    if (idx < NCNT) { int o2 = b0 + texcl + e[i]; off[idx] = o2; cursor[idx] = o2; }
  }
}

__global__ void reorder_kernel(EdgePtrs ep, int* __restrict__ cursor, int* __restrict__ csr) {
  int r = blockIdx.y;
  int e = blockIdx.x * 256 + threadIdx.x;
  if (e >= EE) return;
  const int* ei = ep.p[r];
  int s = ei[e], d = ei[EE + e];
  int pos = atomicAdd(&cursor[r * SMAX + d], 1);
  csr[pos] = s;
}

// ---------------- GEMM: Hb[N x 128] = bf16( x[N x 512] @ W_r )  ----------------
__global__ __launch_bounds__(256, 2)
void gemm_kernel(const float* __restrict__ x, const short* __restrict__ Wt,
                 short* __restrict__ Hb, int N) {
  __shared__ short As[2][128][40];  // 128 rows x 32 k, pad to 40
  __shared__ short Bs[2][128][40];  // 128 cols x 32 k (W transposed), same pad

  int tid = threadIdx.x;
  int wave = tid >> 6, lane = tid & 63;
  int row0 = blockIdx.x * 128;

  int arow = tid >> 1;
  int akh = (tid & 1) * 16;
  bool avalid = (row0 + arow) < N;
  const float* aptr = x + (size_t)(row0 + arow) * 512 + akh;

  int bn = tid & 127;
  int bkh = (tid >> 7) * 16;
  const short* bptr = Wt + (size_t)bn * 512 + bkh;

  int frow = lane & 15;
  int fko = (lane >> 4) * 8;

  f32x4 acc[2][8];
#pragma unroll
  for (int i = 0; i < 2; i++)
#pragma unroll
    for (int j = 0; j < 8; j++) acc[i][j] = (f32x4)0.0f;

  f32x4 a0, a1, a2, a3;
  bf16x8 b0, b1;

#define STAGE_LOAD(T)                                              \
  {                                                                \
    if (avalid) {                                                  \
      const f32x4* ap = (const f32x4*)(aptr + (T) * 32);           \
      a0 = ap[0]; a1 = ap[1]; a2 = ap[2]; a3 = ap[3];              \
    } else {                                                       \
      a0 = (f32x4)0.0f; a1 = (f32x4)0.0f;                          \
      a2 = (f32x4)0.0f; a3 = (f32x4)0.0f;                          \
    }                                                              \
    const short* bp = bptr + (T) * 32;                             \
    b0 = *(const bf16x8*)bp;                                       \
    b1 = *(const bf16x8*)(bp + 8);                                 \
  }

#define STAGE_WRITE(BUF)                                           \
  {                                                                \
    bf16x8 t0, t1;                                                 \
    t0[0] = f2bf(a0.x); t0[1] = f2bf(a0.y); t0[2] = f2bf(a0.z);    \
    t0[3] = f2bf(a0.w); t0[4] = f2bf(a1.x); t0[5] = f2bf(a1.y);    \
    t0[6] = f2bf(a1.z); t0[7] = f2bf(a1.w);                        \
    t1[0] = f2bf(a2.x); t1[1] = f2bf(a2.y); t1[2] = f2bf(a2.z);    \
    t1[3] = f2bf(a2.w); t1[4] = f2bf(a3.x); t1[5] = f2bf(a3.y);    \
    t1[6] = f2bf(a3.z); t1[7] = f2bf(a3.w);                        \
    *(bf16x8*)&As[BUF][arow][akh] = t0;                            \
    *(bf16x8*)&As[BUF][arow][akh + 8] = t1;                        \
    *(bf16x8*)&Bs[BUF][bn][bkh] = b0;                              \
    *(bf16x8*)&Bs[BUF][bn][bkh + 8] = b1;                          \
  }

  STAGE_LOAD(0)
  STAGE_WRITE(0)
  __syncthreads();

  for (int t = 0; t < 16; t++) {
    if (t < 15) STAGE_LOAD(t + 1)
    int cur = t & 1;
    bf16x8 af0 = *(const bf16x8*)&As[cur][wave * 32 + frow][fko];
    bf16x8 af1 = *(const bf16x8*)&As[cur][wave * 32 + 16 + frow][fko];
    bf16x8 bfr[8];
#pragma unroll
    for (int ct = 0; ct < 8; ct++)
      bfr[ct] = *(const bf16x8*)&Bs[cur][ct * 16 + frow][fko];
#pragma unroll
    for (int ct = 0; ct < 8; ct++) {
      acc[0][ct] = __builtin_amdgcn_mfma_f32_16x16x32_bf16(af0, bfr[ct], acc[0][ct], 0, 0, 0);
      acc[1][ct] = __builtin_amdgcn_mfma_f32_16x16x32_bf16(af1, bfr[ct], acc[1][ct], 0, 0, 0);
    }
    if (t < 15) STAGE_WRITE((t + 1) & 1)
    __syncthreads();
  }

  // epilogue: C/D layout col = lane&15, row = (lane>>4)*4 + j  (m89-verified)
  int r4 = (lane >> 4) * 4;
  int cc = lane & 15;
#pragma unroll
  for (int rt = 0; rt < 2; rt++) {
    int rowb = row0 + wave * 32 + rt * 16 + r4;
#pragma unroll
    for (int ct = 0; ct < 8; ct++) {
      int col = ct * 16 + cc;
#pragma unroll
      for (int j = 0; j < 4; j++) {
        if (rowb + j < N) Hb[(size_t)(rowb + j) * 128 + col] = f2bf(acc[rt][ct][j]);
      }
    }
  }
#undef STAGE_LOAD
#undef STAGE_WRITE
}

// ---------------- agg: one wave per dst node, atomic-free ----------------
// out[d] += (1/denom) * sum_e w_e * Hb[src_e],  w_e = exp(lrelu(Ssrc[s]+Sdst[d]))
// csr/off are GLOBAL (off[] holds global positions from the full-NCNT scan).
__global__ void agg_kernel(const int* __restrict__ csr, const int* __restrict__ off,
                           const int* __restrict__ cnt, const float* __restrict__ Ssrc,
                           const float* __restrict__ Sdst, const short* __restrict__ Hb,
                           float* __restrict__ outp, int nDst) {
  int wave = threadIdx.x >> 6, lane = threadIdx.x & 63;
  int d = blockIdx.x * 4 + wave;
  if (d >= nDst) return;
  int deg = cnt[d];
  if (deg == 0) return;
  int start = off[d];
  float sdst = Sdst[d];
  float denom = 0.f, a0 = 0.f, a1 = 0.f;
  for (int i = 0; i < deg; i++) {
    int s = csr[start + i];
    float al = Ssrc[s] + sdst;
    al = al > 0.f ? al : 0.2f * al;
    float w = __expf(al);
    denom += w;
    uint32_t hv = *(const uint32_t*)(Hb + (size_t)s * 128 + lane * 2);
    a0 += w * bf2f(hv & 0xffffu);
    a1 += w * bf2f(hv >> 16);
  }
  float inv = 1.0f / denom;
  float* op = outp + (size_t)d * 128 + lane * 2;
  op[0] += a0 * inv;
  op[1] += a1 * inv;
}

// ---------------- finalize: relu((acc + sum bias)/3) in-place ----------------
__global__ void finalize_kernel(float* __restrict__ out, const float* __restrict__ bias) {
  int idx = blockIdx.x * 256 + threadIdx.x;  // float4 index
  if (idx >= 7360000) return;
  size_t f = (size_t)idx * 4;
  int col = (int)(f & 127);
  int r0, r1, r2;
  if (f < (size_t)NP * 128)            { r0 = 0; r1 = 4; r2 = 7; }
  else if (f < (size_t)(NP + NL) * 128){ r0 = 1; r1 = 3; r2 = 8; }
  else                                 { r0 = 2; r1 = 5; r2 = 6; }
  f32x4 vv = *(f32x4*)(out + f);
#pragma unroll
  for (int j = 0; j < 4; j++) {
    float b = bias[r0 * 128 + col + j] + bias[r1 * 128 + col + j] + bias[r2 * 128 + col + j];
    float val = (vv[j] + b) * (1.0f / 3.0f);
    vv[j] = val > 0.0f ? val : 0.0f;
  }
  *(f32x4*)(out + f) = vv;
}

// ---------------- orchestration ----------------
extern "C" void kernel_launch(void* const* d_in, const int* in_sizes, int n_in,
                              void* d_out, int out_size, void* d_ws, size_t ws_size,
                              hipStream_t stream) {
  const float* x[3] = {(const float*)d_in[0], (const float*)d_in[1], (const float*)d_in[2]};
  const int* ei[9];
  for (int i = 0; i < 9; i++) ei[i] = (const int*)d_in[3 + i];
  const float* W = (const float*)d_in[12];
  const float* att_src = (const float*)d_in[13];
  const float* att_dst = (const float*)d_in[14];
  const float* bias = (const float*)d_in[15];

  char* ws = (char*)d_ws;
  short* Wt     = (short*)(ws + 0);           //  1,179,648 B
  float* v      = (float*)(ws + 1179648);     //     36,864 B
  float* Ssrc   = (float*)(ws + 1216512);     //  3,600,000 B
  float* Sdst   = (float*)(ws + 4816512);     //  3,600,000 B
  int*   cnt    = (int*)  (ws + 8416512);     //  3,600,000 B
  int*   off    = (int*)  (ws + 12016512);    //  3,600,000 B
  int*   cursor = (int*)  (ws + 15616512);    //  3,600,000 B
  int*   bsum   = (int*)  (ws + 19216512);    //      4,096 B
  int*   csr    = (int*)  (ws + 19220608);    // 14,400,000 B
  short* Hb     = (short*)(ws + 33620608);    // 25,600,000 B  (total ~59.2 MB)

  hipMemsetAsync(d_out, 0, (size_t)out_size * 4, stream);
  hipMemsetAsync(cnt, 0, (size_t)NCNT * 4, stream);

  wt_kernel<<<dim3((9 * 512 * 128 + 255) / 256), dim3(256), 0, stream>>>(W, Wt);
  v_kernel<<<dim3(18), dim3(512), 0, stream>>>(W, att_src, att_dst, v);

  // src relations for type T are {3T,3T+1,3T+2}; dst relations per type from RELS table
  scores_kernel<<<dim3(1024), dim3(256), 0, stream>>>(x[0], NP, 0, 0, 4, 7, v, Ssrc, Sdst);
  scores_kernel<<<dim3(1024), dim3(256), 0, stream>>>(x[1], NL, 3, 1, 3, 8, v, Ssrc, Sdst);
  scores_kernel<<<dim3(1024), dim3(256), 0, stream>>>(x[2], NG, 6, 2, 5, 6, v, Ssrc, Sdst);

  EdgePtrs ep;
  for (int i = 0; i < 9; i++) ep.p[i] = ei[i];

  hist_kernel<<<dim3((EE + 255) / 256, 9), dim3(256), 0, stream>>>(ep, cnt);
  const int NBLK = (NCNT + 1023) / 1024;  // 879
  scan1_kernel<<<dim3(NBLK), dim3(256), 0, stream>>>(cnt, bsum);
  scan2_kernel<<<dim3(1), dim3(1024), 0, stream>>>(bsum, NBLK);
  scan3_kernel<<<dim3(NBLK), dim3(256), 0, stream>>>(cnt, bsum, off, cursor);
  reorder_kernel<<<dim3((EE + 255) / 256, 9), dim3(256), 0, stream>>>(ep, cursor, csr);

  static const int srcT[9] = {0, 0, 0, 1, 1, 1, 2, 2, 2};
  static const int dstT[9] = {0, 1, 2, 1, 0, 2, 2, 0, 1};
  static const int Ns[3] = {NP, NL, NG};
  static const size_t outOff[3] = {0, (size_t)NP * 128, (size_t)(NP + NL) * 128};

  for (int r = 0; r < 9; r++) {
    int s = srcT[r], d = dstT[r];
    gemm_kernel<<<dim3((Ns[s] + 127) / 128), dim3(256), 0, stream>>>(
        x[s], Wt + (size_t)r * 128 * 512, Hb, Ns[s]);
    // csr is GLOBAL (off[] holds global scan positions) — do NOT add r*EE here.
    agg_kernel<<<dim3((Ns[d] + 3) / 4), dim3(256), 0, stream>>>(
        csr, off + (size_t)r * SMAX, cnt + (size_t)r * SMAX,
        Ssrc + (size_t)r * SMAX, Sdst + (size_t)r * SMAX, Hb,
        (float*)d_out + outOff[d], Ns[d]);
  }

  finalize_kernel<<<dim3((7360000 + 255) / 256), dim3(256), 0, stream>>>((float*)d_out, bias);
}